// Round 5
// baseline (1059.424 us; speedup 1.0000x reference)
//
#include <hip/hip_runtime.h>
#include <stdint.h>

// B=4, S=2048, D=512, H=8, DK=DV=64
typedef __attribute__((ext_vector_type(8))) short short8;
typedef __attribute__((ext_vector_type(4))) float f32x4;
typedef __attribute__((ext_vector_type(16))) float f32x16;
typedef __attribute__((ext_vector_type(4))) unsigned short ushort4v;
typedef __attribute__((ext_vector_type(4))) int int4v;

__device__ __forceinline__ unsigned short f2bf(float f) {
    union { float f; uint32_t u; } v; v.f = f;
    return (unsigned short)((v.u + 0x7FFFu + ((v.u >> 16) & 1u)) >> 16);
}
__device__ __forceinline__ float bf2f(unsigned short h) {
    union { uint32_t u; float f; } v; v.u = ((uint32_t)h) << 16;
    return v.f;
}
__device__ __forceinline__ float fexp2(float x) {      // raw v_exp_f32 (2^x)
    float r;
    asm("v_exp_f32 %0, %1" : "=v"(r) : "v"(x));
    return r;
}
__device__ __forceinline__ uint32_t cvtpk(float lo, float hi) {  // [bf16(lo)|bf16(hi)<<16]
    uint32_t r;
    asm("v_cvt_pk_bf16_f32 %0, %1, %2" : "=v"(r) : "v"(lo), "v"(hi));
    return r;
}

// ---------------- Kernel 1: tiled transpose W[k][n] f32 -> Wt[n][k] bf16 ----------------
__global__ __launch_bounds__(256) void prep_wt_kernel(
    const float* __restrict__ W0, const float* __restrict__ W1,
    const float* __restrict__ W2, const float* __restrict__ W3,
    unsigned short* __restrict__ Wt)
{
    __shared__ unsigned short tile[64][66];
    const float* W = blockIdx.y == 0 ? W0 : blockIdx.y == 1 ? W1 : blockIdx.y == 2 ? W2 : W3;
    unsigned short* dst = Wt + (size_t)blockIdx.y * (512 * 512);
    const int k0 = (blockIdx.x >> 3) * 64;
    const int n0 = (blockIdx.x & 7) * 64;
    const int nx = threadIdx.x & 63;
    const int ty = threadIdx.x >> 6;
#pragma unroll
    for (int i = 0; i < 16; ++i) {
        const int kl = i * 4 + ty;
        tile[nx][kl] = f2bf(W[(size_t)(k0 + kl) * 512 + n0 + nx]);
    }
    __syncthreads();
#pragma unroll
    for (int i = 0; i < 16; ++i) {
        const int nl = i * 4 + ty;
        dst[(size_t)(n0 + nl) * 512 + k0 + nx] = tile[nl][nx];
    }
}

// ---------------- Kernel 2: Q/K/V projections, N-split 2 ----------------
// grid (256 row-blocks, 2 n-halves, 3 which). which=0: Q -> [bh][s][64] bf16 ;
// which=1: K -> same ; which=2: V -> VT [bh][64][s] bf16
__global__ __launch_bounds__(256) void proj_kernel(
    const float* __restrict__ inQ, const float* __restrict__ inK, const float* __restrict__ inV,
    const unsigned short* __restrict__ Wt,
    unsigned short* __restrict__ outQ, unsigned short* __restrict__ outK,
    unsigned short* __restrict__ outVT)
{
    const int which = blockIdx.z;
    const float* inp = which == 0 ? inQ : which == 1 ? inK : inV;
    const unsigned short* Wtb = Wt + (size_t)which * (512 * 512);
    const int tid = threadIdx.x;
    const int wid = tid >> 6, l = tid & 63;
    const int rt = wid >> 1, ch = wid & 1;
    const int lrow = l & 15, g = l >> 4;
    const int rowbase = blockIdx.x * 32;
    const int nbase = blockIdx.y * 256 + ch * 128;
    const int arow = rowbase + rt * 16 + lrow;

    f32x4 acc[8];
#pragma unroll
    for (int t = 0; t < 8; ++t) acc[t] = (f32x4){0.f, 0.f, 0.f, 0.f};

    for (int k0 = 0; k0 < 512; k0 += 32) {
        const float* ap = inp + (size_t)arow * 512 + k0 + g * 8;
        float4 a0 = *(const float4*)ap;
        float4 a1 = *(const float4*)(ap + 4);
        short8 af;
        af[0] = (short)f2bf(a0.x); af[1] = (short)f2bf(a0.y);
        af[2] = (short)f2bf(a0.z); af[3] = (short)f2bf(a0.w);
        af[4] = (short)f2bf(a1.x); af[5] = (short)f2bf(a1.y);
        af[6] = (short)f2bf(a1.z); af[7] = (short)f2bf(a1.w);
#pragma unroll
        for (int t = 0; t < 8; ++t) {
            const int n = nbase + t * 16 + lrow;
            short8 bf = *(const short8*)(Wtb + (size_t)n * 512 + k0 + g * 8);
            acc[t] = __builtin_amdgcn_mfma_f32_16x16x32_bf16(af, bf, acc[t], 0, 0, 0);
        }
    }

    if (which == 2) {
#pragma unroll
        for (int t = 0; t < 8; ++t) {
            const int n = nbase + t * 16 + lrow;
            const int hh = n >> 6, dd = n & 63;
            const int row0 = rowbase + rt * 16 + g * 4;
            const int bb = row0 >> 11, s0 = row0 & 2047;
            ushort4v pk;
            pk[0] = f2bf(acc[t][0]); pk[1] = f2bf(acc[t][1]);
            pk[2] = f2bf(acc[t][2]); pk[3] = f2bf(acc[t][3]);
            *(ushort4v*)(outVT + ((size_t)(bb * 8 + hh) * 64 + dd) * 2048 + s0) = pk;
        }
    } else {
        unsigned short* dst = which == 0 ? outQ : outK;
#pragma unroll
        for (int t = 0; t < 8; ++t) {
            const int n = nbase + t * 16 + lrow;
            const int hh = n >> 6, dd = n & 63;
#pragma unroll
            for (int r = 0; r < 4; ++r) {
                const int row = rowbase + rt * 16 + g * 4 + r;
                const int bb = row >> 11, s0 = row & 2047;
                dst[((size_t)(bb * 8 + hh) * 2048 + s0) * 64 + dd] = f2bf(acc[t][r]);
            }
        }
    }
}

// ---------------- Kernel 3: fused attention, two-pass recompute, no P buffer ----------------
// WG = 4 waves = one 32-q block of one (b,h). Wave w owns k in [w*512,(w+1)*512).
// S^T via mfma_32x32x16(K,Q): col=q=lane&31, row k=(r&3)+8*(r>>2)+4*(lane>>5).
// Pass A: rowsum of exp (raw v_exp_f32). Pass B: recompute, write normalized attn f32
// from regs, cvt_pk + v_permlane32_swap_b32 -> PV B-frag, accumulate ctx.
// ctx cross-wave reduce: two rounds through 2 x [32][68] LDS (17.9 KB total).
__global__ __launch_bounds__(256, 4) void attn_kernel(
    const unsigned short* __restrict__ Qw, const unsigned short* __restrict__ Kw,
    const unsigned short* __restrict__ VT, const unsigned char* __restrict__ mask,
    float* __restrict__ attn_out, float* __restrict__ ctx)
{
    __shared__ float psum_lds[4][32];
    __shared__ float red0[32][68];   // pad 68: float4-aligned, 4-way max on b128 ops
    __shared__ float red1[32][68];

    // XCD swizzle: xcd = L&7 (dispatch round-robin); each XCD owns 4 consecutive bh.
    const int L = blockIdx.x;
    const int xcd = L & 7, j = L >> 3;
    const int bh = xcd * 4 + (j >> 6);
    const int qb = j & 63;
    const int b = bh >> 3, h = bh & 7;
    const int qg0 = qb * 32;
    const int tid = threadIdx.x, wid = tid >> 6, l = tid & 63;
    const int lq = l & 31, hi = l >> 5;
    const float EXPC = 0.18033688011112042f;   // (1/8)*log2(e)

    // Q B-fragments (persistent): B[d][q], lane: d = 8*hi + j (+16*d4), q = lq
    const unsigned short* qbase = Qw + ((size_t)bh * 2048 + qg0 + lq) * 64 + 8 * hi;
    short8 qf[4];
#pragma unroll
    for (int d4 = 0; d4 < 4; ++d4) qf[d4] = *(const short8*)(qbase + d4 * 16);

    const int k0w = wid * 512;
    const unsigned char* mbase = mask + ((size_t)b * 2048 + qg0 + lq) * 2048 + 4 * hi;
    const unsigned short* kwb = Kw + ((size_t)bh * 2048 + lq) * 64 + 8 * hi;

    // ---- Pass A: rowsum ----
    float psum = 0.f;
    for (int t = 0; t < 16; ++t) {
        const int kb = k0w + t * 32;
        const unsigned short* kp = kwb + (size_t)kb * 64;
        short8 kf0 = *(const short8*)(kp);
        short8 kf1 = *(const short8*)(kp + 16);
        short8 kf2 = *(const short8*)(kp + 32);
        short8 kf3 = *(const short8*)(kp + 48);
        f32x16 sc = (f32x16)(0.f);
        sc = __builtin_amdgcn_mfma_f32_32x32x16_bf16(kf0, qf[0], sc, 0, 0, 0);
        sc = __builtin_amdgcn_mfma_f32_32x32x16_bf16(kf1, qf[1], sc, 0, 0, 0);
        sc = __builtin_amdgcn_mfma_f32_32x32x16_bf16(kf2, qf[2], sc, 0, 0, 0);
        sc = __builtin_amdgcn_mfma_f32_32x32x16_bf16(kf3, qf[3], sc, 0, 0, 0);
#pragma unroll
        for (int c2 = 0; c2 < 4; ++c2) {
            const uint32_t m4 = *(const uint32_t*)(mbase + kb + 8 * c2);
#pragma unroll
            for (int rr = 0; rr < 4; ++rr) {
                const float ev = fexp2(sc[c2 * 4 + rr] * EXPC);
                psum += ((m4 >> (8 * rr)) & 255u) ? 0.f : ev;
            }
        }
    }
    psum += __shfl_xor(psum, 32);          // combine hi/lo k-halves (same q)
    if (l < 32) psum_lds[wid][l] = psum;
    __syncthreads();
    const float rinv = 1.0f / (psum_lds[0][lq] + psum_lds[1][lq] +
                               psum_lds[2][lq] + psum_lds[3][lq]);

    // ---- Pass B: recompute, write attn, PV accumulate ----
    f32x16 acc0 = (f32x16)(0.f), acc1 = (f32x16)(0.f);
    float* abase = attn_out + ((size_t)bh * 2048 + qg0 + lq) * 2048 + 4 * hi;
    const unsigned short* vb0 = VT + ((size_t)bh * 64 + lq) * 2048 + 8 * hi;
    const unsigned short* vb1 = vb0 + (size_t)32 * 2048;

    for (int t = 0; t < 16; ++t) {
        const int kb = k0w + t * 32;
        const unsigned short* kp = kwb + (size_t)kb * 64;
        short8 kf0 = *(const short8*)(kp);
        short8 kf1 = *(const short8*)(kp + 16);
        short8 kf2 = *(const short8*)(kp + 32);
        short8 kf3 = *(const short8*)(kp + 48);
        // hoist V loads: independent of the exp chain, prefetch under QK/exp
        short8 v00 = *(const short8*)(vb0 + kb);
        short8 v01 = *(const short8*)(vb0 + kb + 16);
        short8 v10 = *(const short8*)(vb1 + kb);
        short8 v11 = *(const short8*)(vb1 + kb + 16);
        f32x16 sc = (f32x16)(0.f);
        sc = __builtin_amdgcn_mfma_f32_32x32x16_bf16(kf0, qf[0], sc, 0, 0, 0);
        sc = __builtin_amdgcn_mfma_f32_32x32x16_bf16(kf1, qf[1], sc, 0, 0, 0);
        sc = __builtin_amdgcn_mfma_f32_32x32x16_bf16(kf2, qf[2], sc, 0, 0, 0);
        sc = __builtin_amdgcn_mfma_f32_32x32x16_bf16(kf3, qf[3], sc, 0, 0, 0);

        float e[16];
#pragma unroll
        for (int c2 = 0; c2 < 4; ++c2) {
            const uint32_t m4 = *(const uint32_t*)(mbase + kb + 8 * c2);
#pragma unroll
            for (int rr = 0; rr < 4; ++rr) {
                const float ev = fexp2(sc[c2 * 4 + rr] * EXPC) * rinv;
                e[c2 * 4 + rr] = ((m4 >> (8 * rr)) & 255u) ? 0.f : ev;
            }
        }
        // write normalized attn rows straight from registers (f32)
#pragma unroll
        for (int c2 = 0; c2 < 4; ++c2) {
            float4 st = {e[c2 * 4 + 0], e[c2 * 4 + 1], e[c2 * 4 + 2], e[c2 * 4 + 3]};
            *(float4*)(abase + kb + 8 * c2) = st;
        }
        // pack -> bf16 (cvt_pk), permlane swap -> PV B-fragments, 2 k-halves of 16
#pragma unroll
        for (int kh = 0; kh < 2; ++kh) {
            const int cA = 2 * kh, cB = 2 * kh + 1;
            uint32_t w0 = cvtpk(e[4 * cA + 0], e[4 * cA + 1]);
            uint32_t w1 = cvtpk(e[4 * cB + 0], e[4 * cB + 1]);
            uint32_t w2 = cvtpk(e[4 * cA + 2], e[4 * cA + 3]);
            uint32_t w3 = cvtpk(e[4 * cB + 2], e[4 * cB + 3]);
            asm("v_permlane32_swap_b32 %0, %1" : "+v"(w0), "+v"(w1));
            asm("v_permlane32_swap_b32 %0, %1" : "+v"(w2), "+v"(w3));
            int4v pw = {(int)w0, (int)w2, (int)w1, (int)w3};
            short8 pb = *(short8*)&pw;
            short8 va = kh ? v01 : v00;
            short8 vbt = kh ? v11 : v10;
            acc0 = __builtin_amdgcn_mfma_f32_32x32x16_bf16(va, pb, acc0, 0, 0, 0);
            acc1 = __builtin_amdgcn_mfma_f32_32x32x16_bf16(vbt, pb, acc1, 0, 0, 0);
        }
    }

    // ---- ctx cross-wave reduce: two rounds through 2 buffers ----
    if (wid >= 2) {
        float (*rd)[68] = (wid == 2) ? red0 : red1;
#pragma unroll
        for (int c = 0; c < 4; ++c) {
            const int d = 8 * c + 4 * hi;
            *(float4*)&rd[lq][d]      = (float4){acc0[4*c+0], acc0[4*c+1], acc0[4*c+2], acc0[4*c+3]};
            *(float4*)&rd[lq][d + 32] = (float4){acc1[4*c+0], acc1[4*c+1], acc1[4*c+2], acc1[4*c+3]};
        }
    }
    __syncthreads();
    if (wid < 2) {
        float (*rd)[68] = (wid == 0) ? red0 : red1;
#pragma unroll
        for (int c = 0; c < 4; ++c) {
            const int d = 8 * c + 4 * hi;
            float4 p0 = *(const float4*)&rd[lq][d];
            float4 p1 = *(const float4*)&rd[lq][d + 32];
            acc0[4*c+0] += p0.x; acc0[4*c+1] += p0.y; acc0[4*c+2] += p0.z; acc0[4*c+3] += p0.w;
            acc1[4*c+0] += p1.x; acc1[4*c+1] += p1.y; acc1[4*c+2] += p1.z; acc1[4*c+3] += p1.w;
        }
    }
    __syncthreads();   // red1 reads done before wave 1 overwrites
    if (wid == 1) {
#pragma unroll
        for (int c = 0; c < 4; ++c) {
            const int d = 8 * c + 4 * hi;
            *(float4*)&red1[lq][d]      = (float4){acc0[4*c+0], acc0[4*c+1], acc0[4*c+2], acc0[4*c+3]};
            *(float4*)&red1[lq][d + 32] = (float4){acc1[4*c+0], acc1[4*c+1], acc1[4*c+2], acc1[4*c+3]};
        }
    }
    __syncthreads();
    if (wid == 0) {
        float* cbase = ctx + ((size_t)b * 2048 + qg0 + lq) * 512 + h * 64;
#pragma unroll
        for (int c = 0; c < 4; ++c) {
            const int d = 8 * c + 4 * hi;
            float4 p0 = *(const float4*)&red1[lq][d];
            float4 p1 = *(const float4*)&red1[lq][d + 32];
            float4 s0 = {acc0[4*c+0] + p0.x, acc0[4*c+1] + p0.y,
                         acc0[4*c+2] + p0.z, acc0[4*c+3] + p0.w};
            float4 s1 = {acc1[4*c+0] + p1.x, acc1[4*c+1] + p1.y,
                         acc1[4*c+2] + p1.z, acc1[4*c+3] + p1.w};
            *(float4*)(cbase + d)      = s0;
            *(float4*)(cbase + d + 32) = s1;
        }
    }
}

// ---------------- Kernel 4: fc + residual + LayerNorm (ctx f32), 16-row WGs ----------------
__global__ __launch_bounds__(256) void fc_ln_kernel(
    const float* __restrict__ ctx, const unsigned short* __restrict__ Wtfc,
    const float* __restrict__ resid, const float* __restrict__ gamma,
    const float* __restrict__ beta, float* __restrict__ out)
{
    __shared__ float red[16][4][2];
    const int tid = threadIdx.x;
    const int ch = tid >> 6, l = tid & 63;     // wave = one 128-col quarter
    const int lrow = l & 15, g = l >> 4;
    const int rowbase = blockIdx.x * 16;
    const int arow = rowbase + lrow;

    f32x4 acc[8];
#pragma unroll
    for (int t = 0; t < 8; ++t) acc[t] = (f32x4){0.f, 0.f, 0.f, 0.f};

    for (int k0 = 0; k0 < 512; k0 += 32) {
        const float* ap = ctx + (size_t)arow * 512 + k0 + g * 8;
        float4 a0 = *(const float4*)ap;
        float4 a1 = *(const float4*)(ap + 4);
        short8 af;
        af[0] = (short)f2bf(a0.x); af[1] = (short)f2bf(a0.y);
        af[2] = (short)f2bf(a0.z); af[3] = (short)f2bf(a0.w);
        af[4] = (short)f2bf(a1.x); af[5] = (short)f2bf(a1.y);
        af[6] = (short)f2bf(a1.z); af[7] = (short)f2bf(a1.w);
#pragma unroll
        for (int t = 0; t < 8; ++t) {
            const int n = ch * 128 + t * 16 + lrow;
            short8 bf = *(const short8*)(Wtfc + (size_t)n * 512 + k0 + g * 8);
            acc[t] = __builtin_amdgcn_mfma_f32_16x16x32_bf16(af, bf, acc[t], 0, 0, 0);
        }
    }

    float s1[4] = {0,0,0,0}, s2[4] = {0,0,0,0};
#pragma unroll
    for (int t = 0; t < 8; ++t) {
        const int n = ch * 128 + t * 16 + lrow;
#pragma unroll
        for (int r = 0; r < 4; ++r) {
            const int row = rowbase + g * 4 + r;
            float v = acc[t][r] + resid[(size_t)row * 512 + n];
            acc[t][r] = v;
            s1[r] += v;
            s2[r] += v * v;
        }
    }
#pragma unroll
    for (int r = 0; r < 4; ++r) {
        s1[r] += __shfl_xor(s1[r], 1); s2[r] += __shfl_xor(s2[r], 1);
        s1[r] += __shfl_xor(s1[r], 2); s2[r] += __shfl_xor(s2[r], 2);
        s1[r] += __shfl_xor(s1[r], 4); s2[r] += __shfl_xor(s2[r], 4);
        s1[r] += __shfl_xor(s1[r], 8); s2[r] += __shfl_xor(s2[r], 8);
    }
    if (lrow == 0) {
#pragma unroll
        for (int r = 0; r < 4; ++r) {
            red[g * 4 + r][ch][0] = s1[r];
            red[g * 4 + r][ch][1] = s2[r];
        }
    }
    __syncthreads();
    float mean[4], rstd[4];
#pragma unroll
    for (int r = 0; r < 4; ++r) {
        const int rl = g * 4 + r;
        const float S1 = red[rl][0][0] + red[rl][1][0] + red[rl][2][0] + red[rl][3][0];
        const float S2 = red[rl][0][1] + red[rl][1][1] + red[rl][2][1] + red[rl][3][1];
        mean[r] = S1 * (1.0f / 512.0f);
        const float var = S2 * (1.0f / 512.0f) - mean[r] * mean[r];
        rstd[r] = rsqrtf(var + 1e-5f);
    }
#pragma unroll
    for (int t = 0; t < 8; ++t) {
        const int n = ch * 128 + t * 16 + lrow;
        const float gm = gamma[n], bt = beta[n];
#pragma unroll
        for (int r = 0; r < 4; ++r) {
            const int row = rowbase + g * 4 + r;
            out[(size_t)row * 512 + n] = (acc[t][r] - mean[r]) * rstd[r] * gm + bt;
        }
    }
}

// ---------------- Host launcher ----------------
extern "C" void kernel_launch(void* const* d_in, const int* in_sizes, int n_in,
                              void* d_out, int out_size, void* d_ws, size_t ws_size,
                              hipStream_t stream)
{
    (void)in_sizes; (void)n_in; (void)out_size; (void)ws_size;
    const float* inQ = (const float*)d_in[0];
    const float* inK = (const float*)d_in[1];
    const float* inV = (const float*)d_in[2];
    const unsigned char* mask = (const unsigned char*)d_in[3];  // np.bool_ -> 1 byte
    const float* WQ  = (const float*)d_in[4];
    const float* WK  = (const float*)d_in[5];
    const float* WV  = (const float*)d_in[6];
    const float* Wfc = (const float*)d_in[7];
    const float* gamma = (const float*)d_in[8];
    const float* beta  = (const float*)d_in[9];

    char* ws = (char*)d_ws;
    unsigned short* wsQ   = (unsigned short*)(ws);                           // 8 MB
    unsigned short* wsK   = (unsigned short*)(ws + ((size_t)8  << 20));      // 8 MB
    unsigned short* wsVT  = (unsigned short*)(ws + ((size_t)16 << 20));      // 8 MB
    float*          wsCtx = (float*)         (ws + ((size_t)24 << 20));      // 16 MB (f32)
    unsigned short* wsWt  = (unsigned short*)(ws + ((size_t)40 << 20));      // 2 MB

    float* out_ln   = (float*)d_out;
    float* out_attn = out_ln + (size_t)4 * 2048 * 512;

    prep_wt_kernel<<<dim3(64, 4), dim3(256), 0, stream>>>(WQ, WK, WV, Wfc, wsWt);
    proj_kernel<<<dim3(256, 2, 3), dim3(256), 0, stream>>>(inQ, inK, inV, wsWt,
                                                           wsQ, wsK, wsVT);
    attn_kernel<<<dim3(2048), dim3(256), 0, stream>>>(wsQ, wsK, wsVT, mask,
                                                      out_attn, wsCtx);
    fc_ln_kernel<<<dim3(512), dim3(256), 0, stream>>>(wsCtx, wsWt + (size_t)3 * 512 * 512,
                                                      inQ, gamma, beta, out_ln);
}